// Round 2
// baseline (685.667 us; speedup 1.0000x reference)
//
#include <hip/hip_runtime.h>

// SOM BMU one-hot via split-bf16 MFMA GEMM. R10 structure:
//   som_prep : w -> w3 (8-slot swizzled B-frags: [wh x4 | wl x4], 512 KB) + wsq
//   som_main : MFMA GEMM, register-direct B (R8 style, no LDS), but 48 rows
//              per wave (3 row-groups) -> w3 L2 stream 1.6 GB -> 1.07 GB.
//              2084 single-wave blocks, ~2 waves/SIMD, 3 acc chains.
//              argmin + fused nontemporal one-hot write.
//   som_pass2: fp64 re-solve, one 1024-thread block per flagged row
//
// R9 post-mortem: LDS-shared B regressed +15 us. Corrected model: MFMA floor
// is 38 us (19.4 SIMD-cyc per 16x16x32, NOT 4.8 -- that was per-CU), and the
// LDS path costs ~30 us on the per-CU LDS pipe (12 waves x 512 b128 x 12 cyc)
// plus 32 vmcnt-drain barriers -- it replaced the 46 us L2 stream with equal
// cost. R10 attacks the L2 term without LDS: traffic = (N/rows_per_wave) *
// 512 KB; 48 rows/wave -> 31 us < MFMA 38 us floor. Numerics identical to R8.

typedef __attribute__((ext_vector_type(8))) short bf16x8;   // 8 bf16 = 4 VGPR
typedef __attribute__((ext_vector_type(4))) float f32x4;

#define SOM_K 1024
#define SOM_D 128
#define SOM_N 100000
#define MARGIN 0.02f
#define FLAG_CAP 8192

// d_ws layout (bytes):
#define WS_WSQ   64        // 1024 f32  (4 KB)
#define WS_W3    8192      // 64 tiles x 8 slots x 64 lanes x 8 bf16 (512 KB)
#define WS_FLAGS 532480    // 8192 int  (32 KB) -> ends ~565 KB

static __device__ __forceinline__ unsigned short f2bf(float f) {
    unsigned u = __float_as_uint(f);
    return (unsigned short)((u + 0x7FFFu + ((u >> 16) & 1u)) >> 16);  // RNE
}
static __device__ __forceinline__ float bf2f(unsigned short h) {
    return __uint_as_float(((unsigned)h) << 16);
}

// ---- prep: w -> w3 (swizzled split-bf16, 8 slots) + exact wsq -------------
// w3 element for (proto n, inner kk in [0,256)): s=kk>>5 (slot), q=(kk>>3)&3,
// j=kk&7, nt=n>>4, c=n&15:  flat = ((nt*8+s)*64 + q*16 + c)*8 + j.
// Inner vector is [wh(dims 0..127) | wl(dims 0..127)].
__global__ __launch_bounds__(256) void som_prep(
    const float* __restrict__ w, unsigned short* __restrict__ w3,
    float* __restrict__ wsq)
{
    __shared__ float ws_[16][SOM_D];     // 8 KB staging for 16 protos
    const int nt = blockIdx.x;           // tile 0..63
    const int tid = threadIdx.x;

    const float* src = w + (size_t)nt * 16 * SOM_D;
    #pragma unroll
    for (int r = 0; r < 8; ++r) {
        const int e = r * 256 + tid;
        ws_[e >> 7][e & 127] = src[e];
    }
    __syncthreads();

    unsigned short* dst = w3 + (size_t)nt * 4096;
    #pragma unroll
    for (int r = 0; r < 2; ++r) {
        const int G = r * 256 + tid;     // 0..511
        const int s = G >> 6;            // slot 0..7
        const int l = G & 63;            // lane
        const int c = l & 15, q = l >> 4;
        bf16x8 v;
        #pragma unroll
        for (int j = 0; j < 8; ++j) {
            const int kk = 32 * s + 8 * q + j;       // 0..255
            const int d = kk & 127;
            const float f = ws_[c][d];
            const unsigned short h = f2bf(f);
            v[j] = (short)((kk & 128) ? f2bf(f - bf2f(h)) : h);  // wl : wh
        }
        *(bf16x8*)(dst + G * 8) = v;
    }

    if (tid < 16) {
        double s = 0.0;
        #pragma unroll 16
        for (int d = 0; d < SOM_D; ++d) {
            double v = (double)ws_[tid][d];
            s += v * v;
        }
        wsq[nt * 16 + tid] = (float)s;
    }
}

// ---- main: MFMA GEMM + argmin + fused one-hot write -----------------------
// 48 rows per single-wave block (3 groups of 16), 2084 blocks (tail-guarded).
// B register-direct from L2 (8 x dwordx4 per tile); L2 stream 1.07 GB.
__global__ __launch_bounds__(64, 2) void som_main(
    const float* __restrict__ x,
    const unsigned short* __restrict__ w3,
    const float* __restrict__ wsq,
    float* __restrict__ out,
    int* __restrict__ flag_count,
    int* __restrict__ flag_list)
{
    const int lane = threadIdx.x;
    const int c = lane & 15;
    const int q = lane >> 4;
    const int R0 = blockIdx.x * 48;          // 2084 * 48 = 100032 (tail clamped)

    // a-frags: A[m=lane&15][k=8q+j], three 16-row groups, hi+lo (96 VGPR).
    bf16x8 ah[3][4], al[3][4];
    #pragma unroll
    for (int g = 0; g < 3; ++g) {
        int rbase = R0 + 16 * g + c;
        if (rbase > SOM_N - 1) rbase = SOM_N - 1;   // tail clamp (read-only)
        const float* xp = x + (size_t)rbase * SOM_D + 8 * q;
        #pragma unroll
        for (int s = 0; s < 4; ++s) {
            float4 v0 = *(const float4*)(xp + 32 * s);
            float4 v1 = *(const float4*)(xp + 32 * s + 4);
            float xv[8] = {v0.x, v0.y, v0.z, v0.w, v1.x, v1.y, v1.z, v1.w};
            bf16x8 hh, ll;
            #pragma unroll
            for (int j = 0; j < 8; ++j) {
                unsigned short h = f2bf(xv[j]);
                hh[j] = (short)h;
                ll[j] = (short)f2bf(xv[j] - bf2f(h));
            }
            ah[g][s] = hh; al[g][s] = ll;
        }
    }

    float best[3][4], sec[3][4];
    int bk[3][4];
    #pragma unroll
    for (int g = 0; g < 3; ++g)
        #pragma unroll
        for (int r = 0; r < 4; ++r) { best[g][r] = 1e30f; sec[g][r] = 1e30f; bk[g][r] = 0; }

    // coalesced b-frag base: lane*16B; slot stride 1 KB; tile stride 8 KB
    const unsigned short* wbase = w3 + lane * 8;

    #pragma unroll 1
    for (int nt = 0; nt < 64; ++nt) {
        const int n0 = nt * 16;
        const unsigned short* wp = wbase + (size_t)nt * 4096;
        bf16x8 b[8];
        #pragma unroll
        for (int s = 0; s < 8; ++s) b[s] = *(const bf16x8*)(wp + 512 * s);
        const float wq = wsq[n0 + c];

        f32x4 acc[3];
        #pragma unroll
        for (int g = 0; g < 3; ++g) acc[g] = (f32x4){0.f, 0.f, 0.f, 0.f};

        #pragma unroll
        for (int s = 0; s < 4; ++s) {   // xh * wh
            #pragma unroll
            for (int g = 0; g < 3; ++g)
                acc[g] = __builtin_amdgcn_mfma_f32_16x16x32_bf16(ah[g][s], b[s], acc[g], 0, 0, 0);
        }
        #pragma unroll
        for (int s = 0; s < 4; ++s) {   // xh * wl
            #pragma unroll
            for (int g = 0; g < 3; ++g)
                acc[g] = __builtin_amdgcn_mfma_f32_16x16x32_bf16(ah[g][s], b[4 + s], acc[g], 0, 0, 0);
        }
        #pragma unroll
        for (int s = 0; s < 4; ++s) {   // xl * wh -- reuses b[0..3]
            #pragma unroll
            for (int g = 0; g < 3; ++g)
                acc[g] = __builtin_amdgcn_mfma_f32_16x16x32_bf16(al[g][s], b[s], acc[g], 0, 0, 0);
        }

        #pragma unroll
        for (int g = 0; g < 3; ++g) {
            #pragma unroll
            for (int r = 0; r < 4; ++r) {
                float s0 = wq - 2.f * acc[g][r];
                if (s0 < best[g][r]) { sec[g][r] = best[g][r]; best[g][r] = s0; bk[g][r] = n0 + c; }
                else if (s0 < sec[g][r]) sec[g][r] = s0;
            }
        }
    }

    // reduce across the 16 c-lanes of each quad-group (result in all lanes)
    #pragma unroll
    for (int g = 0; g < 3; ++g) {
        #pragma unroll
        for (int r = 0; r < 4; ++r) {
            float b0v = best[g][r], s0v = sec[g][r];
            int k0 = bk[g][r];
            #pragma unroll
            for (int m = 1; m < 16; m <<= 1) {
                float ob = __shfl_xor(b0v, m);
                float os = __shfl_xor(s0v, m);
                int   ok = __shfl_xor(k0, m);
                if (ob < b0v || (ob == b0v && ok < k0)) {
                    s0v = fminf(b0v, os); b0v = ob; k0 = ok;
                } else {
                    s0v = fminf(s0v, ob);
                }
            }
            best[g][r] = b0v; sec[g][r] = s0v; bk[g][r] = k0;
        }
    }

    if (c == 0) {   // lanes 0,16,32,48 hold rows g*16 + 4q + r
        #pragma unroll
        for (int g = 0; g < 3; ++g) {
            #pragma unroll
            for (int r = 0; r < 4; ++r) {
                const int row = R0 + g * 16 + 4 * q + r;
                if (row < SOM_N && sec[g][r] - best[g][r] < MARGIN) {
                    int i = atomicAdd(flag_count, 1);
                    if (i < FLAG_CAP) flag_list[i] = row;
                }
            }
        }
    }

    // fused one-hot write: row rr's bmu lives in quad (rr>>2)&3, reg rr&3
    #pragma unroll 1
    for (int rr = 0; rr < 48; ++rr) {
        const int row = R0 + rr;
        if (row >= SOM_N) break;         // tail guard (wave-uniform)
        const int g = rr >> 4, qq = (rr >> 2) & 3, r = rr & 3;
        const int b = __shfl(bk[g][r], qq << 4);
        f32x4* op = (f32x4*)(out + (size_t)row * SOM_K);
        #pragma unroll
        for (int j = 0; j < 4; ++j) {
            const int e = j * 64 + lane;
            f32x4 v = {0.f, 0.f, 0.f, 0.f};
            if ((b >> 2) == e) v[b & 3] = 1.0f;
            __builtin_nontemporal_store(v, op + e);
        }
    }
}

// ---- pass2: fp64 re-solve, one 1024-thread block per flagged row ----------
__global__ __launch_bounds__(1024) void som_pass2(
    const float* __restrict__ x,
    const float* __restrict__ w,
    float* __restrict__ out,
    const int* __restrict__ flag_count,
    const int* __restrict__ flag_list)
{
    __shared__ float xs[SOM_D];
    __shared__ double rbest[16];
    __shared__ int    rk[16];

    const int tid  = threadIdx.x;          // == proto k
    const int lane = tid & 63;
    const int wv   = tid >> 6;             // wave 0..15
    int cnt = *flag_count;
    if (cnt > FLAG_CAP) cnt = FLAG_CAP;

    for (int i = blockIdx.x; i < cnt; i += gridDim.x) {
        const int row = flag_list[i];
        __syncthreads();                   // guard xs/red reuse
        if (tid < SOM_D) xs[tid] = x[(size_t)row * SOM_D + tid];
        __syncthreads();

        // exact fp64 score for proto k = tid (contiguous per-lane w stream)
        const float* wk = w + (size_t)tid * SOM_D;
        double s0 = 0.0, s1 = 0.0;
        #pragma unroll
        for (int d = 0; d < SOM_D; d += 4) {
            float4 wv4 = *(const float4*)(wk + d);
            double w0 = (double)wv4.x, w1 = (double)wv4.y;
            double w2 = (double)wv4.z, w3 = (double)wv4.w;
            s0 += w0 * (w0 - 2.0 * (double)xs[d])     + w2 * (w2 - 2.0 * (double)xs[d + 2]);
            s1 += w1 * (w1 - 2.0 * (double)xs[d + 1]) + w3 * (w3 - 2.0 * (double)xs[d + 3]);
        }
        double sc = s0 + s1;
        int bk = tid;

        // wave argmin (tie -> smaller k)
        #pragma unroll
        for (int off = 32; off > 0; off >>= 1) {
            double os = __shfl_down(sc, off);
            int    ok = __shfl_down(bk, off);
            if (os < sc || (os == sc && ok < bk)) { sc = os; bk = ok; }
        }
        if (lane == 0) { rbest[wv] = sc; rk[wv] = bk; }
        __syncthreads();

        if (tid == 0) {
            double b = rbest[0]; int k0 = rk[0];
            #pragma unroll
            for (int v = 1; v < 16; ++v) {
                if (rbest[v] < b || (rbest[v] == b && rk[v] < k0)) { b = rbest[v]; k0 = rk[v]; }
            }
            rk[0] = k0;
        }
        __syncthreads();
        const int bmu = rk[0];

        out[(size_t)row * SOM_K + tid] = (tid == bmu) ? 1.0f : 0.0f;
    }
}

extern "C" void kernel_launch(void* const* d_in, const int* in_sizes, int n_in,
                              void* d_out, int out_size, void* d_ws, size_t ws_size,
                              hipStream_t stream) {
    const float* x = (const float*)d_in[0];
    const float* w = (const float*)d_in[1];
    float* out = (float*)d_out;

    char* ws = (char*)d_ws;
    int*            flag_count = (int*)ws;
    float*          wsq        = (float*)(ws + WS_WSQ);
    unsigned short* w3         = (unsigned short*)(ws + WS_W3);
    int*            flag_list  = (int*)(ws + WS_FLAGS);

    (void)hipMemsetAsync(d_ws, 0, 64, stream);   // flag counter

    som_prep<<<64, 256, 0, stream>>>(w, w3, wsq);
    som_main<<<2084, 64, 0, stream>>>(x, w3, wsq, out, flag_count, flag_list);
    som_pass2<<<256, 1024, 0, stream>>>(x, w, out, flag_count, flag_list);
}

// Round 3
// 639.863 us; speedup vs baseline: 1.0716x; 1.0716x over previous
//
#include <hip/hip_runtime.h>

// SOM BMU one-hot via split-bf16 MFMA GEMM. R11 structure:
//   som_prep : w -> w3 (8-slot swizzled B-frags: [wh x4 | wl x4], 512 KB) + wsq
//   som_gemm : 32 rows/wave, 3125 single-wave blocks. Register DOUBLE-BUFFERED
//              B (even/odd tile bodies, bA/bB statically indexed): next tile's
//              8 dwordx4 issue before current tile's 24-MFMA cluster -> L2
//              latency hidden in-wave. Emits 16-B record {best,sec,bk} per row.
//   som_write: record -> MARGIN flag + one-hot nontemporal stream (400 MB),
//              25000 x 256 blocks -> write-BW-bound with huge TLP.
//   som_pass2: fp64 re-solve, one 1024-thread block per flagged row
//
// R10 post-mortem: som_main 262 us, MfmaUtil 11.9%, Occupancy 14.3%
// (~1.15 waves/SIMD). MFMA work = 38 us fixed (4.8M x 19.4 SIMD-cyc / 1024);
// 38/262 == measured MfmaUtil -> duration is latency serialization, NOT L2
// bandwidth: single-buffered B exposes ~450 cyc/tile with no TLP to cover it,
// and the fused 400 MB write only reached ~1.5 TB/s in 1-wave blocks.
// R11 attacks both: in-wave prefetch (latency) + separate write kernel (TLP).

typedef __attribute__((ext_vector_type(8))) short bf16x8;   // 8 bf16 = 4 VGPR
typedef __attribute__((ext_vector_type(4))) float f32x4;

#define SOM_K 1024
#define SOM_D 128
#define SOM_N 100000
#define MARGIN 0.02f
#define FLAG_CAP 8192

// d_ws layout (bytes):
#define WS_WSQ   64        // 1024 f32  (4 KB)
#define WS_W3    8192      // 64 tiles x 8 slots x 64 lanes x 8 bf16 (512 KB)
#define WS_FLAGS 532480    // 8192 int  (32 KB)
#define WS_REC   565248    // 100000 x float4 records (1.6 MB) -> ends ~2.2 MB

static __device__ __forceinline__ unsigned short f2bf(float f) {
    unsigned u = __float_as_uint(f);
    return (unsigned short)((u + 0x7FFFu + ((u >> 16) & 1u)) >> 16);  // RNE
}
static __device__ __forceinline__ float bf2f(unsigned short h) {
    return __uint_as_float(((unsigned)h) << 16);
}

// ---- prep: w -> w3 (swizzled split-bf16, 8 slots) + exact wsq -------------
// w3 element for (proto n, inner kk in [0,256)): s=kk>>5 (slot), q=(kk>>3)&3,
// j=kk&7, nt=n>>4, c=n&15:  flat = ((nt*8+s)*64 + q*16 + c)*8 + j.
// Inner vector is [wh(dims 0..127) | wl(dims 0..127)].
__global__ __launch_bounds__(256) void som_prep(
    const float* __restrict__ w, unsigned short* __restrict__ w3,
    float* __restrict__ wsq)
{
    __shared__ float ws_[16][SOM_D];     // 8 KB staging for 16 protos
    const int nt = blockIdx.x;           // tile 0..63
    const int tid = threadIdx.x;

    const float* src = w + (size_t)nt * 16 * SOM_D;
    #pragma unroll
    for (int r = 0; r < 8; ++r) {
        const int e = r * 256 + tid;
        ws_[e >> 7][e & 127] = src[e];
    }
    __syncthreads();

    unsigned short* dst = w3 + (size_t)nt * 4096;
    #pragma unroll
    for (int r = 0; r < 2; ++r) {
        const int G = r * 256 + tid;     // 0..511
        const int s = G >> 6;            // slot 0..7
        const int l = G & 63;            // lane
        const int c = l & 15, q = l >> 4;
        bf16x8 v;
        #pragma unroll
        for (int j = 0; j < 8; ++j) {
            const int kk = 32 * s + 8 * q + j;       // 0..255
            const int d = kk & 127;
            const float f = ws_[c][d];
            const unsigned short h = f2bf(f);
            v[j] = (short)((kk & 128) ? f2bf(f - bf2f(h)) : h);  // wl : wh
        }
        *(bf16x8*)(dst + G * 8) = v;
    }

    if (tid < 16) {
        double s = 0.0;
        #pragma unroll 16
        for (int d = 0; d < SOM_D; ++d) {
            double v = (double)ws_[tid][d];
            s += v * v;
        }
        wsq[nt * 16 + tid] = (float)s;
    }
}

// ---- gemm: MFMA + argmin -> per-row record --------------------------------
// One tile's compute against buffer B_ (8 frags) for tile index NT_.
#define TILE_BODY(B_, NT_)                                                     \
    {                                                                          \
        const int n0 = (NT_) * 16;                                             \
        const float wq = wsq[n0 + c];                                          \
        f32x4 a0 = {0.f, 0.f, 0.f, 0.f}, a1 = {0.f, 0.f, 0.f, 0.f};            \
        _Pragma("unroll")                                                      \
        for (int s = 0; s < 4; ++s) {   /* xh * wh */                          \
            a0 = __builtin_amdgcn_mfma_f32_16x16x32_bf16(ah[0][s], B_[s], a0, 0, 0, 0); \
            a1 = __builtin_amdgcn_mfma_f32_16x16x32_bf16(ah[1][s], B_[s], a1, 0, 0, 0); \
        }                                                                      \
        _Pragma("unroll")                                                      \
        for (int s = 0; s < 4; ++s) {   /* xh * wl */                          \
            a0 = __builtin_amdgcn_mfma_f32_16x16x32_bf16(ah[0][s], B_[4 + s], a0, 0, 0, 0); \
            a1 = __builtin_amdgcn_mfma_f32_16x16x32_bf16(ah[1][s], B_[4 + s], a1, 0, 0, 0); \
        }                                                                      \
        _Pragma("unroll")                                                      \
        for (int s = 0; s < 4; ++s) {   /* xl * wh -- reuses B_[0..3] */       \
            a0 = __builtin_amdgcn_mfma_f32_16x16x32_bf16(al[0][s], B_[s], a0, 0, 0, 0); \
            a1 = __builtin_amdgcn_mfma_f32_16x16x32_bf16(al[1][s], B_[s], a1, 0, 0, 0); \
        }                                                                      \
        _Pragma("unroll")                                                      \
        for (int r = 0; r < 4; ++r) {                                          \
            float s0 = wq - 2.f * a0[r];                                       \
            if (s0 < best[0][r]) { sec[0][r] = best[0][r]; best[0][r] = s0; bk[0][r] = n0 + c; } \
            else if (s0 < sec[0][r]) sec[0][r] = s0;                           \
            float s1 = wq - 2.f * a1[r];                                       \
            if (s1 < best[1][r]) { sec[1][r] = best[1][r]; best[1][r] = s1; bk[1][r] = n0 + c; } \
            else if (s1 < sec[1][r]) sec[1][r] = s1;                           \
        }                                                                      \
    }

__global__ __launch_bounds__(64, 2) void som_gemm(
    const float* __restrict__ x,
    const unsigned short* __restrict__ w3,
    const float* __restrict__ wsq,
    float4* __restrict__ rec)
{
    const int lane = threadIdx.x;
    const int c = lane & 15;
    const int q = lane >> 4;
    const int R0 = blockIdx.x * 32;          // 3125 * 32 = 100000 exact

    // a-frags: A[m=lane&15][k=8q+j], two 16-row groups, hi+lo (64 VGPR).
    bf16x8 ah[2][4], al[2][4];
    #pragma unroll
    for (int g = 0; g < 2; ++g) {
        const float* xp = x + (size_t)(R0 + 16 * g + c) * SOM_D + 8 * q;
        #pragma unroll
        for (int s = 0; s < 4; ++s) {
            float4 v0 = *(const float4*)(xp + 32 * s);
            float4 v1 = *(const float4*)(xp + 32 * s + 4);
            float xv[8] = {v0.x, v0.y, v0.z, v0.w, v1.x, v1.y, v1.z, v1.w};
            bf16x8 hh, ll;
            #pragma unroll
            for (int j = 0; j < 8; ++j) {
                unsigned short h = f2bf(xv[j]);
                hh[j] = (short)h;
                ll[j] = (short)f2bf(xv[j] - bf2f(h));
            }
            ah[g][s] = hh; al[g][s] = ll;
        }
    }

    float best[2][4], sec[2][4];
    int bk[2][4];
    #pragma unroll
    for (int g = 0; g < 2; ++g)
        #pragma unroll
        for (int r = 0; r < 4; ++r) { best[g][r] = 1e30f; sec[g][r] = 1e30f; bk[g][r] = 0; }

    // coalesced b-frag base: lane*16B; slot stride 1 KB; tile stride 8 KB
    const unsigned short* wbase = w3 + lane * 8;

    // register double-buffer: bA holds even tile, bB odd tile.
    bf16x8 bA[8], bB[8];
    #pragma unroll
    for (int s = 0; s < 8; ++s) bA[s] = *(const bf16x8*)(wbase + 512 * s);  // tile 0

    #pragma unroll 1
    for (int ntp = 0; ntp < 32; ++ntp) {
        const int ntE = 2 * ntp;
        const int ntO = ntE + 1;
        // prefetch odd tile into bB (issues before bA's MFMA cluster)
        {
            const unsigned short* wp = wbase + (size_t)ntO * 4096;
            #pragma unroll
            for (int s = 0; s < 8; ++s) bB[s] = *(const bf16x8*)(wp + 512 * s);
        }
        TILE_BODY(bA, ntE)
        // prefetch next even tile into bA (clamped reload of tile 0 at end)
        {
            const int ntN = (ntp < 31) ? ntE + 2 : 0;
            const unsigned short* wp = wbase + (size_t)ntN * 4096;
            #pragma unroll
            for (int s = 0; s < 8; ++s) bA[s] = *(const bf16x8*)(wp + 512 * s);
        }
        TILE_BODY(bB, ntO)
    }

    // reduce across the 16 c-lanes of each quad-group (result in all lanes)
    #pragma unroll
    for (int g = 0; g < 2; ++g) {
        #pragma unroll
        for (int r = 0; r < 4; ++r) {
            float b0v = best[g][r], s0v = sec[g][r];
            int k0 = bk[g][r];
            #pragma unroll
            for (int m = 1; m < 16; m <<= 1) {
                float ob = __shfl_xor(b0v, m);
                float os = __shfl_xor(s0v, m);
                int   ok = __shfl_xor(k0, m);
                if (ob < b0v || (ob == b0v && ok < k0)) {
                    s0v = fminf(b0v, os); b0v = ob; k0 = ok;
                } else {
                    s0v = fminf(s0v, ob);
                }
            }
            best[g][r] = b0v; sec[g][r] = s0v; bk[g][r] = k0;
        }
    }

    if (c == 0) {   // lanes 0,16,32,48 hold rows g*16 + 4q + r
        #pragma unroll
        for (int g = 0; g < 2; ++g) {
            #pragma unroll
            for (int r = 0; r < 4; ++r) {
                const int row = R0 + g * 16 + 4 * q + r;
                float4 rv;
                rv.x = best[g][r];
                rv.y = sec[g][r];
                rv.z = __int_as_float(bk[g][r]);
                rv.w = 0.f;
                rec[row] = rv;
            }
        }
    }
}

// ---- write: record -> flag + one-hot stream -------------------------------
// 4 rows per 256-thread block (1 row/wave); 25000 blocks; write-BW-bound.
__global__ __launch_bounds__(256) void som_write(
    const float4* __restrict__ rec,
    float* __restrict__ out,
    int* __restrict__ flag_count,
    int* __restrict__ flag_list)
{
    const int lane = threadIdx.x & 63;
    const int wv   = threadIdx.x >> 6;
    const int row  = blockIdx.x * 4 + wv;        // 25000 * 4 = 100000 exact

    const float4 r = rec[row];                   // broadcast (same addr/wave)
    const int b = __float_as_int(r.z);

    if (lane == 0 && (r.y - r.x < MARGIN)) {
        int i = atomicAdd(flag_count, 1);
        if (i < FLAG_CAP) flag_list[i] = row;
    }

    f32x4* op = (f32x4*)(out + (size_t)row * SOM_K);
    #pragma unroll
    for (int j = 0; j < 4; ++j) {
        const int e = j * 64 + lane;
        f32x4 v = {0.f, 0.f, 0.f, 0.f};
        if ((b >> 2) == e) v[b & 3] = 1.0f;
        __builtin_nontemporal_store(v, op + e);
    }
}

// ---- pass2: fp64 re-solve, one 1024-thread block per flagged row ----------
__global__ __launch_bounds__(1024) void som_pass2(
    const float* __restrict__ x,
    const float* __restrict__ w,
    float* __restrict__ out,
    const int* __restrict__ flag_count,
    const int* __restrict__ flag_list)
{
    __shared__ float xs[SOM_D];
    __shared__ double rbest[16];
    __shared__ int    rk[16];

    const int tid  = threadIdx.x;          // == proto k
    const int lane = tid & 63;
    const int wv   = tid >> 6;             // wave 0..15
    int cnt = *flag_count;
    if (cnt > FLAG_CAP) cnt = FLAG_CAP;

    for (int i = blockIdx.x; i < cnt; i += gridDim.x) {
        const int row = flag_list[i];
        __syncthreads();                   // guard xs/red reuse
        if (tid < SOM_D) xs[tid] = x[(size_t)row * SOM_D + tid];
        __syncthreads();

        // exact fp64 score for proto k = tid (contiguous per-lane w stream)
        const float* wk = w + (size_t)tid * SOM_D;
        double s0 = 0.0, s1 = 0.0;
        #pragma unroll
        for (int d = 0; d < SOM_D; d += 4) {
            float4 wv4 = *(const float4*)(wk + d);
            double w0 = (double)wv4.x, w1 = (double)wv4.y;
            double w2 = (double)wv4.z, w3 = (double)wv4.w;
            s0 += w0 * (w0 - 2.0 * (double)xs[d])     + w2 * (w2 - 2.0 * (double)xs[d + 2]);
            s1 += w1 * (w1 - 2.0 * (double)xs[d + 1]) + w3 * (w3 - 2.0 * (double)xs[d + 3]);
        }
        double sc = s0 + s1;
        int bk = tid;

        // wave argmin (tie -> smaller k)
        #pragma unroll
        for (int off = 32; off > 0; off >>= 1) {
            double os = __shfl_down(sc, off);
            int    ok = __shfl_down(bk, off);
            if (os < sc || (os == sc && ok < bk)) { sc = os; bk = ok; }
        }
        if (lane == 0) { rbest[wv] = sc; rk[wv] = bk; }
        __syncthreads();

        if (tid == 0) {
            double b = rbest[0]; int k0 = rk[0];
            #pragma unroll
            for (int v = 1; v < 16; ++v) {
                if (rbest[v] < b || (rbest[v] == b && rk[v] < k0)) { b = rbest[v]; k0 = rk[v]; }
            }
            rk[0] = k0;
        }
        __syncthreads();
        const int bmu = rk[0];

        out[(size_t)row * SOM_K + tid] = (tid == bmu) ? 1.0f : 0.0f;
    }
}

extern "C" void kernel_launch(void* const* d_in, const int* in_sizes, int n_in,
                              void* d_out, int out_size, void* d_ws, size_t ws_size,
                              hipStream_t stream) {
    const float* x = (const float*)d_in[0];
    const float* w = (const float*)d_in[1];
    float* out = (float*)d_out;

    char* ws = (char*)d_ws;
    int*            flag_count = (int*)ws;
    float*          wsq        = (float*)(ws + WS_WSQ);
    unsigned short* w3         = (unsigned short*)(ws + WS_W3);
    int*            flag_list  = (int*)(ws + WS_FLAGS);
    float4*         rec        = (float4*)(ws + WS_REC);

    (void)hipMemsetAsync(d_ws, 0, 64, stream);   // flag counter

    som_prep<<<64, 256, 0, stream>>>(w, w3, wsq);
    som_gemm<<<3125, 64, 0, stream>>>(x, w3, wsq, rec);
    som_write<<<25000, 256, 0, stream>>>(rec, out, flag_count, flag_list);
    som_pass2<<<256, 1024, 0, stream>>>(x, w, out, flag_count, flag_list);
}